// Round 4
// baseline (210.574 us; speedup 1.0000x reference)
//
#include <hip/hip_runtime.h>
#include <math.h>

// Group-limited MoE router, T=131072 tokens x E=256 experts.
// 8 lanes per token, one lane per expert-group (32 experts).
// Round 4: all cross-lane exchanges via DPP (VALU pipe) instead of
// ds_swizzle (LDS pipe + lgkmcnt stalls). Exchange patterns live within
// 8-lane segments: xor1=quad_perm(0xB1), xor2=quad_perm(0x4E),
// other-quad=row_half_mirror(0x141) (== xor4 whenever values are
// quad-uniform, which holds at every use site). Ordering math (expf +
// IEEE div) untouched -> ids bit-match np reference (round-2 lesson).

#define DPP_XOR1 0xB1   // quad_perm [1,0,3,2]
#define DPP_XOR2 0x4E   // quad_perm [2,3,0,1]
#define DPP_HM   0x141  // row_half_mirror: lane s <-> 7-s (= s^7 in 8)

#define DPPI(x, ctrl) __builtin_amdgcn_update_dpp(0, (x), (ctrl), 0xF, 0xF, true)
#define DPPF(x, ctrl) __int_as_float(DPPI(__float_as_int(x), (ctrl)))

__global__ __launch_bounds__(256) void router_topk_kernel(
    const float* __restrict__ logits,
    const float* __restrict__ bias,
    float* __restrict__ out_w,
    float* __restrict__ out_id,
    int T)
{
    const float NEGINF = -__builtin_inff();
    const int tid = threadIdx.x;
    const int s = tid & 7;                      // expert-group owned by this lane
    const int token = blockIdx.x * 32 + (tid >> 3);
    if (token >= T) return;

    const float* row = logits + (size_t)token * 256 + s * 32;
    const float* brw = bias + s * 32;

    float v[8][4];
    int   ix[8][4];

    // ---- load 32 logits, exact sigmoid (matches np ordering), add bias ----
    #pragma unroll
    for (int c = 0; c < 8; ++c) {
        float4 l = ((const float4*)row)[c];
        float4 b = ((const float4*)brw)[c];
        #pragma unroll
        for (int k = 0; k < 4; ++k) {
            float x = (&l.x)[k];
            v[c][k] = 1.0f / (1.0f + expf(-x)) + (&b.x)[k];
            ix[c][k] = s * 32 + c * 4 + k;
        }
    }

    // ---- group score: sum of top-2 of my 32 biased values ----
    float t1 = NEGINF, t2 = NEGINF;
    #pragma unroll
    for (int c = 0; c < 8; ++c) {
        #pragma unroll
        for (int k = 0; k < 4; ++k) {
            float val = v[c][k];
            t2 = fmaxf(t2, fminf(t1, val));
            t1 = fmaxf(t1, val);
        }
    }
    const float gs = t1 + t2;

    // ---- rank my group among the 8; keep top-4 (ties -> lower group id) ----
    // Partner scores gs[s^m] for m=1..7 via chained DPP movs.
    // Tie-break: partner j = s^m wins tie iff j < s iff (s & highbit(m)).
    {
        float g1 = DPPF(gs, DPP_XOR1);          // gs[s^1]
        float g2 = DPPF(gs, DPP_XOR2);          // gs[s^2]
        float g3 = DPPF(g1, DPP_XOR2);          // gs[s^3]
        float g7 = DPPF(gs, DPP_HM);            // gs[s^7]
        float g6 = DPPF(g7, DPP_XOR1);          // gs[s^6]
        float g5 = DPPF(g7, DPP_XOR2);          // gs[s^5]
        float g4 = DPPF(g6, DPP_XOR2);          // gs[s^4]
        int rank = 0;
        rank += (g1 > gs || (g1 == gs && (s & 1))) ? 1 : 0;
        rank += (g2 > gs || (g2 == gs && (s & 2))) ? 1 : 0;
        rank += (g3 > gs || (g3 == gs && (s & 2))) ? 1 : 0;
        rank += (g4 > gs || (g4 == gs && (s & 4))) ? 1 : 0;
        rank += (g5 > gs || (g5 == gs && (s & 4))) ? 1 : 0;
        rank += (g6 > gs || (g6 == gs && (s & 4))) ? 1 : 0;
        rank += (g7 > gs || (g7 == gs && (s & 4))) ? 1 : 0;
        const bool selected = rank < 4;
        #pragma unroll
        for (int c = 0; c < 8; ++c) {
            #pragma unroll
            for (int k = 0; k < 4; ++k)
                v[c][k] = selected ? v[c][k] : NEGINF;
        }
    }

    // ---- sort each chunk of 4 descending (ties -> lower idx first) ----
    #pragma unroll
    for (int c = 0; c < 8; ++c) {
        #define CE(a,b) { \
            bool sw = (v[c][a] < v[c][b]) || (v[c][a] == v[c][b] && ix[c][a] > ix[c][b]); \
            float tv = sw ? v[c][b] : v[c][a]; \
            float uv = sw ? v[c][a] : v[c][b]; \
            int   ti = sw ? ix[c][b] : ix[c][a]; \
            int   ui = sw ? ix[c][a] : ix[c][b]; \
            v[c][a] = tv; v[c][b] = uv; ix[c][a] = ti; ix[c][b] = ui; }
        CE(0,1) CE(2,3) CE(0,2) CE(1,3) CE(1,2)
        #undef CE
    }

    // ---- 8 rounds: global argmax over 64 stream heads, advance winner ----
    float keepV = 0.0f; int keepI = 0;
    const int sbase8 = s << 3;
    #pragma unroll
    for (int r = 0; r < 8; ++r) {
        // depth-3 tournament over 8 chunk heads; strict > keeps lower chunk
        // (= lower index) on ties -> lowest-index-first.
        #define PICK(av, ai, bv, bi, rv, ri) { \
            bool t = ((bv) > (av)); \
            rv = t ? (bv) : (av); ri = t ? (bi) : (ai); }
        float w0v, w1v, w2v, w3v, x0v, x1v, bv;
        int   w0i, w1i, w2i, w3i, x0i, x1i, bi;
        PICK(v[0][0], ix[0][0], v[1][0], ix[1][0], w0v, w0i)
        PICK(v[2][0], ix[2][0], v[3][0], ix[3][0], w1v, w1i)
        PICK(v[4][0], ix[4][0], v[5][0], ix[5][0], w2v, w2i)
        PICK(v[6][0], ix[6][0], v[7][0], ix[7][0], w3v, w3i)
        PICK(w0v, w0i, w1v, w1i, x0v, x0i)
        PICK(w2v, w2i, w3v, w3i, x1v, x1i)
        PICK(x0v, x0i, x1v, x1i, bv, bi)
        #undef PICK
        // 8-lane butterfly argmax via DPP; index tie-break keeps all lanes
        // consistent. After xor1+xor2 each quad is uniform, so half-mirror
        // combines the two quads exactly like xor4.
        #define BFLY(CTRL) { \
            float ov = DPPF(bv, CTRL); int oi = DPPI(bi, CTRL); \
            bool t = (ov > bv) || (ov == bv && oi < bi); \
            bv = t ? ov : bv; bi = t ? oi : bi; }
        BFLY(DPP_XOR1) BFLY(DPP_XOR2) BFLY(DPP_HM)
        #undef BFLY
        if (s == r) { keepV = bv; keepI = bi; }
        const int d = (bi >> 2) - sbase8;   // my chunk index if winner is mine
        #pragma unroll
        for (int c = 0; c < 8; ++c) {
            bool hit = (d == c);
            v[c][0]  = hit ? v[c][1]  : v[c][0];
            ix[c][0] = hit ? ix[c][1] : ix[c][0];
            v[c][1]  = hit ? v[c][2]  : v[c][1];
            ix[c][1] = hit ? ix[c][2] : ix[c][1];
            v[c][2]  = hit ? v[c][3]  : v[c][2];
            ix[c][2] = hit ? ix[c][3] : ix[c][2];
            v[c][3]  = hit ? NEGINF   : v[c][3];
        }
    }

    // ---- recover sigmoid score, renormalize, scale, store (coalesced) ----
    // Butterfly sum: t2 is quad-uniform before stage 3, so HM == xor4;
    // addition pattern identical to rounds 1/3 -> bit-identical weights.
    float w = keepV - bias[keepI];
    float sum = w;
    sum += DPPF(sum, DPP_XOR1);
    sum += DPPF(sum, DPP_XOR2);
    sum += DPPF(sum, DPP_HM);
    w = w / (sum + 1e-20f) * 2.5f;

    out_w[(size_t)token * 8 + s]  = w;
    out_id[(size_t)token * 8 + s] = (float)keepI;
}

extern "C" void kernel_launch(void* const* d_in, const int* in_sizes, int n_in,
                              void* d_out, int out_size, void* d_ws, size_t ws_size,
                              hipStream_t stream) {
    const float* logits = (const float*)d_in[0];
    const float* bias   = (const float*)d_in[1];
    const int E = in_sizes[1];          // 256
    const int T = in_sizes[0] / E;      // 131072
    float* out_w  = (float*)d_out;
    float* out_id = out_w + (size_t)T * 8;
    const int blocks = (T + 31) / 32;
    router_topk_kernel<<<blocks, 256, 0, stream>>>(logits, bias, out_w, out_id, T);
}